// Round 7
// baseline (45.113 us; speedup 1.0000x reference)
//
#include <hip/hip_runtime.h>

#define NROB 32
#define SEQ 12
#define LOBS 52
#define HID 256
#define LOUT 2
#define BATCH 1024
#define KIN 624            // SEQ*LOBS
#define SPB 8              // samples per chunk/block
#define NSD 24             // SEQ*LOUT
#define NBLK 320           // 8 xcds x 40 slots
#define SLOTS 40

__device__ __forceinline__ void fma4(float4& a, const float4 w, const float s) {
  a.x = fmaf(w.x, s, a.x);
  a.y = fmaf(w.y, s, a.y);
  a.z = fmaf(w.z, s, a.z);
  a.w = fmaf(w.w, s, a.w);
}

// ---------------- L2 warm kernel ----------------
// 1024 blocks; block bx warms the weights of robots {x, x+8, x+16, x+24},
// x = bx&7, into the L2 of the XCD it runs on (dispatch round-robin: xcd=bx%8)
// -- the same r&7 mapping k_fused uses. Pure streaming reads, BW-bound.
__global__ __launch_bounds__(256) void k_warm(
    const float* __restrict__ Wi, const float* __restrict__ bi,
    const float* __restrict__ W1, const float* __restrict__ W2,
    const float* __restrict__ W3, const float* __restrict__ Wo,
    float* __restrict__ ws) {
  const int bx = blockIdx.x;
  const int x = bx & 7;
  const int lane = (bx >> 3) * 256 + threadIdx.x;  // 0..32767 within xcd group
  float s = 0.f;
#pragma unroll
  for (int rr = 0; rr < 4; ++rr) {
    const int r = x + rr * 8;
    const float4* p = (const float4*)(Wi + (size_t)r * (KIN * HID));
    for (int i = lane; i < (KIN * HID) / 4; i += 32768) {
      const float4 v = p[i];
      s += v.x + v.y + v.z + v.w;
    }
    p = (const float4*)(W1 + (size_t)r * (HID * HID));
    for (int i = lane; i < (HID * HID) / 4; i += 32768) {
      const float4 v = p[i];
      s += v.x + v.y + v.z + v.w;
    }
    p = (const float4*)(W2 + (size_t)r * (HID * HID));
    for (int i = lane; i < (HID * HID) / 4; i += 32768) {
      const float4 v = p[i];
      s += v.x + v.y + v.z + v.w;
    }
    p = (const float4*)(W3 + (size_t)r * (HID * HID));
    for (int i = lane; i < (HID * HID) / 4; i += 32768) {
      const float4 v = p[i];
      s += v.x + v.y + v.z + v.w;
    }
    p = (const float4*)(Wo + (size_t)r * (SEQ * HID * LOUT));
    for (int i = lane; i < (SEQ * HID * LOUT) / 4; i += 32768) {
      const float4 v = p[i];
      s += v.x + v.y + v.z + v.w;
    }
    p = (const float4*)(bi + (size_t)r * (SEQ * HID));
    for (int i = lane; i < (SEQ * HID) / 4; i += 32768) {
      const float4 v = p[i];
      s += v.x + v.y + v.z + v.w;
    }
  }
  ws[bx] = s;  // keep loads alive; deterministic; never read back
}

// ---------------- fused MLP kernel (R6 verbatim) ----------------
template <int ROWS, int XS>
__device__ __forceinline__ void stream8(const float* __restrict__ wp,
                                        const float* xb, float4* acc) {
  static_assert(ROWS % 16 == 0, "ROWS multiple of 16");
  constexpr int G = ROWS / 8;  // even
  float4 A[8], B[8];
#pragma unroll
  for (int j = 0; j < 8; ++j) A[j] = *(const float4*)(wp + j * HID);
#pragma unroll
  for (int j = 0; j < 8; ++j) B[j] = *(const float4*)(wp + (8 + j) * HID);
#pragma unroll
  for (int g = 0; g < G; g += 2) {
    const int k = g * 8;
#pragma unroll
    for (int m = 0; m < SPB; ++m) {
      const float4 xa = *(const float4*)(xb + m * XS + k);
      const float4 xc = *(const float4*)(xb + m * XS + k + 4);
      fma4(acc[m], A[0], xa.x);
      fma4(acc[m], A[1], xa.y);
      fma4(acc[m], A[2], xa.z);
      fma4(acc[m], A[3], xa.w);
      fma4(acc[m], A[4], xc.x);
      fma4(acc[m], A[5], xc.y);
      fma4(acc[m], A[6], xc.z);
      fma4(acc[m], A[7], xc.w);
    }
    if (g + 2 < G) {
#pragma unroll
      for (int j = 0; j < 8; ++j)
        A[j] = *(const float4*)(wp + (size_t)(k + 16 + j) * HID);
    }
#pragma unroll
    for (int m = 0; m < SPB; ++m) {
      const float4 xa = *(const float4*)(xb + m * XS + k + 8);
      const float4 xc = *(const float4*)(xb + m * XS + k + 12);
      fma4(acc[m], B[0], xa.x);
      fma4(acc[m], B[1], xa.y);
      fma4(acc[m], B[2], xa.z);
      fma4(acc[m], B[3], xa.w);
      fma4(acc[m], B[4], xc.x);
      fma4(acc[m], B[5], xc.y);
      fma4(acc[m], B[6], xc.z);
      fma4(acc[m], B[7], xc.w);
    }
    if (g + 3 < G) {
#pragma unroll
      for (int j = 0; j < 8; ++j)
        B[j] = *(const float4*)(wp + (size_t)(k + 24 + j) * HID);
    }
  }
}

__global__ __launch_bounds__(512, 2) void k_fused(
    const float* __restrict__ obs, const int* __restrict__ mask,
    const int* __restrict__ ids, const float* __restrict__ Wi,
    const float* __restrict__ bi, const float* __restrict__ W1,
    const float* __restrict__ b1, const float* __restrict__ W2,
    const float* __restrict__ b2, const float* __restrict__ W3,
    const float* __restrict__ b3, const float* __restrict__ Wo,
    const float* __restrict__ bo, float* __restrict__ out) {
  __shared__ int s_cnt[NROB];
  __shared__ int s_wc[8];
  __shared__ int s_bm[SPB], s_vm[SPB], s_mb[SPB];
  __shared__ float s_ind[SPB][SEQ];
  __shared__ __align__(16) float s_x0[SPB * KIN];   // 19968B; reused as X2
  __shared__ __align__(16) float s_P[4][SPB][HID];  // 32768B; reused as Wo tile
  __shared__ __align__(16) float s_x1[SPB][HID];    // 8192B

  const int t = threadIdx.x;
  const int bx = blockIdx.x;

  if (t < NROB) s_cnt[t] = 0;
  if (t < SPB) s_bm[t] = 0;
  __syncthreads();
  const int id0 = ids[t];
  const int id1 = ids[t + 512];
  atomicAdd(&s_cnt[id0], 1);
  atomicAdd(&s_cnt[id1], 1);
  __syncthreads();

  int myr = -1, mybase = 0;
  {
    int maxbucket = 0;
    for (int x = 0; x < 8; ++x) {
      int bsum = 0;
      for (int r = x; r < NROB; r += 8) bsum += (s_cnt[r] + SPB - 1) >> 3;
      maxbucket = max(maxbucket, bsum);
    }
    if (maxbucket <= SLOTS) {
      const int myxcd = bx & 7, myslot = bx >> 3;
      int slot = 0;
      for (int r = myxcd; r < NROB; r += 8) {
        const int nch = (s_cnt[r] + SPB - 1) >> 3;
        if (myr < 0 && myslot >= slot && myslot < slot + nch) {
          myr = r;
          mybase = (myslot - slot) * SPB;
        }
        slot += nch;
      }
    } else {
      int ch = 0;
      for (int r = 0; r < NROB; ++r) {
        const int nch = (s_cnt[r] + SPB - 1) >> 3;
        if (myr < 0 && bx >= ch && bx < ch + nch) {
          myr = r;
          mybase = (bx - ch) * SPB;
        }
        ch += nch;
      }
    }
  }
  if (myr < 0) return;
  const int mycnt = s_cnt[myr];

  {
    const int wv = t >> 6;
    const unsigned lane = t & 63;
    const unsigned long long m0 = __ballot(id0 == myr);
    const unsigned long long m1 = __ballot(id1 == myr);
    if (lane == 0) s_wc[wv] = __popcll(m0);
    __syncthreads();
    const unsigned long long below = (1ull << lane) - 1ull;
    int pre0 = 0;
    for (int i = 0; i < wv; ++i) pre0 += s_wc[i];
    if (id0 == myr) {
      const int j = pre0 + __popcll(m0 & below) - mybase;
      if (j >= 0 && j < SPB) s_bm[j] = t;
    }
    __syncthreads();
    if (lane == 0) s_wc[wv] = __popcll(m1);
    __syncthreads();
    int pre1 = 0;
    for (int i = 0; i < wv; ++i) pre1 += s_wc[i];
    __shared__ int s_h0;
    if (t == 0) s_h0 = 0;
    __syncthreads();
    if (lane == 0) atomicAdd(&s_h0, __popcll(m0));
    __syncthreads();
    if (id1 == myr) {
      const int j = s_h0 + pre1 + __popcll(m1 & below) - mybase;
      if (j >= 0 && j < SPB) s_bm[j] = t + 512;
    }
    __syncthreads();
  }
  if (t < SPB) {
    const int v = (mybase + t) < mycnt;
    s_vm[t] = v;
    int mb = 0xFFF;
    if (v) {
      mb = 0;
      const int b = s_bm[t];
      for (int s = 0; s < SEQ; ++s) mb |= (mask[b * SEQ + s] != 0) << s;
    }
    s_mb[t] = mb;
  }
  __syncthreads();
  if (t < SPB * SEQ) {
    const int m = t / SEQ, s = t - m * SEQ;
    s_ind[m][s] = ((s_mb[m] >> s) & 1) ? 0.f : 1.f;
  }
  for (int q = t; q < SPB * (KIN / 4); q += 512) {
    const int m = q / 156, f4 = q - m * 156;
    const int s = f4 / 13;
    float4 v = {0.f, 0.f, 0.f, 0.f};
    if (!((s_mb[m] >> s) & 1))
      v = *(const float4*)(obs + (size_t)s_bm[m] * KIN + f4 * 4);
    *(float4*)&s_x0[m * KIN + f4 * 4] = v;
  }
  __syncthreads();

  const int w = t >> 6, lane = t & 63;
  float* Pp = &s_P[w >> 1][0][lane * 4];

  {
    float4 acc[SPB];
#pragma unroll
    for (int m = 0; m < SPB; ++m) acc[m] = {0.f, 0.f, 0.f, 0.f};
    const float* Wr = Wi + ((size_t)myr * KIN + w * 80) * HID + lane * 4;
    const float* xb = &s_x0[w * 80];
    if (w < 7)
      stream8<80, KIN>(Wr, xb, acc);
    else
      stream8<64, KIN>(Wr, xb, acc);
    if ((w & 1) == 0) {
#pragma unroll
      for (int m = 0; m < SPB; ++m) *(float4*)(Pp + m * HID) = acc[m];
    }
    __syncthreads();
    if (w & 1) {
#pragma unroll
      for (int m = 0; m < SPB; ++m) {
        float4 c = *(const float4*)(Pp + m * HID);
        c.x += acc[m].x;
        c.y += acc[m].y;
        c.z += acc[m].z;
        c.w += acc[m].w;
        *(float4*)(Pp + m * HID) = c;
      }
    }
    __syncthreads();
    {
      const int m = t >> 6, c4 = (t & 63) * 4;
      const float4 p0 = *(const float4*)&s_P[0][m][c4];
      const float4 p1 = *(const float4*)&s_P[1][m][c4];
      const float4 p2 = *(const float4*)&s_P[2][m][c4];
      const float4 p3 = *(const float4*)&s_P[3][m][c4];
      float4 a = {p0.x + p1.x + p2.x + p3.x, p0.y + p1.y + p2.y + p3.y,
                  p0.z + p1.z + p2.z + p3.z, p0.w + p1.w + p2.w + p3.w};
      const float* br = bi + (size_t)myr * SEQ * HID + c4;
#pragma unroll
      for (int s = 0; s < SEQ; ++s)
        fma4(a, *(const float4*)(br + s * HID), s_ind[m][s]);
      float4 o = {fmaxf(a.x, 0.f), fmaxf(a.y, 0.f), fmaxf(a.z, 0.f),
                  fmaxf(a.w, 0.f)};
      *(float4*)&s_x1[m][c4] = o;
    }
    __syncthreads();
  }

  float* X2 = s_x0;
  const float* Ws[3] = {W1, W2, W3};
  const float* bs[3] = {b1, b2, b3};
#pragma unroll
  for (int L = 0; L < 3; ++L) {
    const float* Xin = (L & 1) ? X2 : &s_x1[0][0];
    float* Xout = (L & 1) ? &s_x1[0][0] : X2;
    float4 acc[SPB];
#pragma unroll
    for (int m = 0; m < SPB; ++m) acc[m] = {0.f, 0.f, 0.f, 0.f};
    const float* Wr = Ws[L] + ((size_t)myr * HID + w * 32) * HID + lane * 4;
    stream8<32, HID>(Wr, Xin + w * 32, acc);
    if ((w & 1) == 0) {
#pragma unroll
      for (int m = 0; m < SPB; ++m) *(float4*)(Pp + m * HID) = acc[m];
    }
    __syncthreads();
    if (w & 1) {
#pragma unroll
      for (int m = 0; m < SPB; ++m) {
        float4 c = *(const float4*)(Pp + m * HID);
        c.x += acc[m].x;
        c.y += acc[m].y;
        c.z += acc[m].z;
        c.w += acc[m].w;
        *(float4*)(Pp + m * HID) = c;
      }
    }
    __syncthreads();
    {
      const int m = t >> 6, c4 = (t & 63) * 4;
      const float4 p0 = *(const float4*)&s_P[0][m][c4];
      const float4 p1 = *(const float4*)&s_P[1][m][c4];
      const float4 p2 = *(const float4*)&s_P[2][m][c4];
      const float4 p3 = *(const float4*)&s_P[3][m][c4];
      const float4 bv = *(const float4*)(bs[L] + (size_t)myr * HID + c4);
      float4 o = {fmaxf(p0.x + p1.x + p2.x + p3.x + bv.x, 0.f),
                  fmaxf(p0.y + p1.y + p2.y + p3.y + bv.y, 0.f),
                  fmaxf(p0.z + p1.z + p2.z + p3.z + bv.z, 0.f),
                  fmaxf(p0.w + p1.w + p2.w + p3.w + bv.w, 0.f)};
      *(float4*)(Xout + m * HID + c4) = o;
    }
    __syncthreads();
  }

  float* S = &s_P[0][0][0];
  {
    const float* Wop = Wo + (size_t)myr * SEQ * HID * LOUT;
    for (int q = t; q < (NSD * HID) / 4; q += 512) {
      const float4 v = *(const float4*)(Wop + q * 4);
      const int flat = q * 4;
      const int s = flat >> 9;
      const int k = (flat & 511) >> 1;
      S[(k + 0) * 25 + s * 2 + 0] = v.x;
      S[(k + 0) * 25 + s * 2 + 1] = v.y;
      S[(k + 1) * 25 + s * 2 + 0] = v.z;
      S[(k + 1) * 25 + s * 2 + 1] = v.w;
    }
  }
  __syncthreads();
  if (t < SPB * NSD) {
    const int m = t / NSD, sd = t - m * NSD;
    float a = bo[(size_t)myr * NSD + sd];
    const float* xp = X2 + m * HID;
#pragma unroll 8
    for (int k = 0; k < HID; ++k) a = fmaf(xp[k], S[k * 25 + sd], a);
    if (s_vm[m]) out[(size_t)s_bm[m] * NSD + sd] = a;
  }
}

extern "C" void kernel_launch(void* const* d_in, const int* in_sizes, int n_in,
                              void* d_out, int out_size, void* d_ws, size_t ws_size,
                              hipStream_t stream) {
  const float* obs = (const float*)d_in[0];
  const int* mask = (const int*)d_in[1];
  const int* ids = (const int*)d_in[2];
  const float* Wi = (const float*)d_in[3];
  const float* bi = (const float*)d_in[4];
  const float* W1 = (const float*)d_in[5];
  const float* b1 = (const float*)d_in[6];
  const float* W2 = (const float*)d_in[7];
  const float* b2 = (const float*)d_in[8];
  const float* W3 = (const float*)d_in[9];
  const float* b3 = (const float*)d_in[10];
  const float* Wo = (const float*)d_in[11];
  const float* bo = (const float*)d_in[12];
  float* out = (float*)d_out;
  float* ws = (float*)d_ws;

  hipLaunchKernelGGL(k_warm, dim3(1024), dim3(256), 0, stream, Wi, bi, W1, W2,
                     W3, Wo, ws);
  hipLaunchKernelGGL(k_fused, dim3(NBLK), dim3(512), 0, stream, obs, mask, ids,
                     Wi, bi, W1, b1, W2, b2, W3, b3, Wo, bo, out);
}